// Round 5
// baseline (256.380 us; speedup 1.0000x reference)
//
#include <hip/hip_runtime.h>

// ZeroPad2d: in [32,2048,2048] f32 -> out [32,2050,2050] f32, pad=1.
// R5 = R4's aligned-store layout + fat blocks (unbundled from R3's NT stores).
//   - 2048 bulk blocks x 256 threads; each block copies 32 consecutive rows
//     (#pragma unroll 4 -> 8 independent 16B loads in flight per thread)
//   - all f32x4 STORES 16B-aligned (row start s is even; shift body by 2*(s%4)/2);
//     loads are 4B-misaligned 16B (reads tolerate this; L2 absorbs line splits)
//   - row-edge chunk built scalar by its owning lane; lane 0 writes the
//     leftover 2 floats (head when p=1, tail when p=0)
//   - 64 trailing blocks zero the top/bottom pad rows
//   - NO nontemporal hints (R3 showed NT stores regress on this pattern)
// Every output element is written on every call (harness does not re-poison).

#define CH 32
#define H  2048
#define W  2048
#define HPAD 2050
#define WPAD 2050
#define ROWS_PER_BLOCK 32
#define BULK_BLOCKS ((CH * H) / ROWS_PER_BLOCK)   // 2048

typedef float f32x4 __attribute__((ext_vector_type(4)));
typedef float f32x2 __attribute__((ext_vector_type(2)));

__global__ __launch_bounds__(256) void zeropad_rows(const float* __restrict__ in,
                                                    float* __restrict__ out) {
    const unsigned bid = blockIdx.x;
    const unsigned t   = threadIdx.x;

    if (bid < BULK_BLOCKS) {
        const unsigned row0 = bid * ROWS_PER_BLOCK;
        #pragma unroll 4
        for (unsigned i = 0; i < ROWS_PER_BLOCK; ++i) {
            const unsigned row = row0 + i;
            const unsigned c = row >> 11;            // row / 2048
            const unsigned h = row & 2047u;          // row % 2048
            const float* src = in + ((size_t)row << 11);
            const size_t  s  = (size_t)(c * HPAD + h + 1u) * WPAD;  // row start (even)
            float* dstrow    = out + s;
            const unsigned p = ((unsigned)s & 3u) >> 1;             // 0/1 -> shift 0/2
            float* body      = dstrow + 2u * p;                     // 16B-aligned
            const float* ls  = src + 2u * p;         // body chunk k reads ls[4k-1..4k+2]

            #pragma unroll
            for (int kk = 0; kk < 2; ++kk) {
                const unsigned k = t + 256u * kk;                   // 0..511
                f32x4 v;
                const bool edge = (p == 0u) ? (k == 0u) : (k == 511u);
                if (!edge) {
                    __builtin_memcpy(&v, ls + 4u * k - 1u, 16);     // 4B-aligned load
                } else if (p == 0u) {
                    v[0] = 0.f;       v[1] = src[0];    v[2] = src[1];    v[3] = src[2];
                } else {
                    v[0] = src[2045]; v[1] = src[2046]; v[2] = src[2047]; v[3] = 0.f;
                }
                *(f32x4*)(body + 4u * k) = v;                       // 16B-aligned store
            }
            if (t == 0) {
                if (p == 0u) { dstrow[2048] = src[2047]; dstrow[2049] = 0.f; }
                else         { dstrow[0]    = 0.f;       dstrow[1]    = src[0]; }
            }
        }
    } else {
        // top/bottom zero pad rows: 32 channels x 2 rows, 2050 zeros each
        const unsigned idx = bid - BULK_BLOCKS;      // 0..63
        const unsigned c   = idx >> 1;
        const unsigned y   = (idx & 1u) ? (HPAD - 1u) : 0u;
        float* dst = out + (size_t)(c * HPAD + y) * WPAD;           // 8B-aligned

        const f32x2 z2 = (f32x2)0.f;
        #pragma unroll
        for (int kk = 0; kk < 4; ++kk) {
            const unsigned k = t + 256u * kk;                       // 0..1023
            *(f32x2*)(dst + 2u * k) = z2;                           // 8B-aligned store
        }
        if (t == 0) { dst[2048] = 0.f; dst[2049] = 0.f; }
    }
}

extern "C" void kernel_launch(void* const* d_in, const int* in_sizes, int n_in,
                              void* d_out, int out_size, void* d_ws, size_t ws_size,
                              hipStream_t stream) {
    const float* in = (const float*)d_in[0];
    float* out = (float*)d_out;
    const int blocks = BULK_BLOCKS + CH * 2;         // 2048 bulk + 64 pad-row blocks
    zeropad_rows<<<blocks, 256, 0, stream>>>(in, out);
}

// Round 6
// 199.536 us; speedup vs baseline: 1.2849x; 1.2849x over previous
//
#include <hip/hip_runtime.h>

// ZeroPad2d: in [32,2048,2048] f32 -> out [32,2050,2050] f32, pad=1.
// R6: both-sides-aligned copy. 1 row per 256-thread block (small blocks won
// twice over fat blocks). Thread t loads two ALIGNED f32x4 chunks of its row;
// the +1-float input->output shift is realigned in-register with one shuffle
// per chunk; all stores are 16B-aligned. Wave-boundary lanes patch their
// carry element with a scalar load (~7/row). Row parity p=(s%4)/2 alternates
// per row and is block-uniform -> no divergence on the p branch.
// 64 trailing blocks zero the top/bottom pad rows.
// Every output element is written on every call (harness does not re-poison).

#define CH 32
#define H  2048
#define W  2048
#define HPAD 2050
#define WPAD 2050

typedef float f32x4 __attribute__((ext_vector_type(4)));
typedef float f32x2 __attribute__((ext_vector_type(2)));

__global__ __launch_bounds__(256) void zeropad_rows(const float* __restrict__ in,
                                                    float* __restrict__ out) {
    const unsigned bid = blockIdx.x;
    const unsigned t   = threadIdx.x;

    if (bid < CH * H) {
        const unsigned c = bid >> 11;            // row / 2048
        const unsigned h = bid & 2047u;          // row % 2048
        const float* src = in + ((size_t)bid << 11);
        const size_t  s  = (size_t)(c * HPAD + h + 1u) * WPAD;  // row start (even)
        float* dstrow    = out + s;
        const unsigned p = ((unsigned)s & 3u) >> 1;             // 0 or 1 (block-uniform)
        float* body      = dstrow + 2u * p;                     // 16B-aligned

        // fully aligned input loads: chunks t and t+256 of this row
        f32x4 A0 = *(const f32x4*)(src + 4u * t);
        f32x4 A1 = *(const f32x4*)(src + 4u * t + 1024u);
        const unsigned lane = t & 63u;

        f32x4 v0, v1;
        if (p == 0u) {
            // body chunk k = src[4k-1 .. 4k+2] = { A_{k-1}[3], A_k[0..2] }
            float prev0 = __shfl_up(A0[3], 1);
            float prev1 = __shfl_up(A1[3], 1);
            if (lane == 0u) {                    // carry crosses wave boundary
                if (t > 0u) prev0 = src[4u * t - 1u];
                prev1 = src[4u * t + 1023u];     // 4*(t+256) - 1
            }
            v0[0] = (t == 0u) ? 0.f : prev0;     // k=0: left pad zero
            v0[1] = A0[0]; v0[2] = A0[1]; v0[3] = A0[2];
            v1[0] = prev1;
            v1[1] = A1[0]; v1[2] = A1[1]; v1[3] = A1[2];
        } else {
            // body chunk k = src[4k+1 .. 4k+4] = { A_k[1..3], A_{k+1}[0] }
            float nxt0 = __shfl_down(A0[0], 1);
            float nxt1 = __shfl_down(A1[0], 1);
            if (lane == 63u) {                   // carry crosses wave boundary
                nxt0 = src[4u * t + 4u];
                if (t < 255u) nxt1 = src[4u * t + 1028u];   // 4*(t+256) + 4
            }
            v0[0] = A0[1]; v0[1] = A0[2]; v0[2] = A0[3];
            v0[3] = nxt0;
            v1[0] = A1[1]; v1[1] = A1[2]; v1[2] = A1[3];
            v1[3] = (t == 255u) ? 0.f : nxt1;    // k=511: right pad zero
        }
        *(f32x4*)(body + 4u * t)           = v0;             // 16B-aligned stores
        *(f32x4*)(body + 4u * t + 1024u)   = v1;

        if (t == 0u) {                           // leftover 2 floats per row
            if (p == 0u) { dstrow[2048] = src[2047]; dstrow[2049] = 0.f; }
            else         { dstrow[0]    = 0.f;       dstrow[1]    = src[0]; }
        }
    } else {
        // top/bottom zero pad rows: 32 channels x 2 rows, 2050 zeros each
        const unsigned idx = bid - CH * H;       // 0..63
        const unsigned c   = idx >> 1;
        const unsigned y   = (idx & 1u) ? (HPAD - 1u) : 0u;
        float* dst = out + (size_t)(c * HPAD + y) * WPAD;    // 8B-aligned

        const f32x2 z2 = (f32x2)0.f;
        #pragma unroll
        for (int kk = 0; kk < 4; ++kk) {
            const unsigned k = t + 256u * kk;                // 0..1023
            *(f32x2*)(dst + 2u * k) = z2;                    // 8B-aligned store
        }
        if (t == 0u) { dst[2048] = 0.f; dst[2049] = 0.f; }
    }
}

extern "C" void kernel_launch(void* const* d_in, const int* in_sizes, int n_in,
                              void* d_out, int out_size, void* d_ws, size_t ws_size,
                              hipStream_t stream) {
    const float* in = (const float*)d_in[0];
    float* out = (float*)d_out;
    const int blocks = CH * H + CH * 2;          // 65536 copy rows + 64 pad rows
    zeropad_rows<<<blocks, 256, 0, stream>>>(in, out);
}